// Round 7
// baseline (3336.157 us; speedup 1.0000x reference)
//
#include <hip/hip_runtime.h>
#include <hip/hip_bf16.h>
#include <cstdint>

// ---------------------------------------------------------------------------
// HeteroGNN: 2-layer hetero-SAGE (7 rel, 1.6M edges) + classifier, 100k nodes.
// Design C6:
//  * CSR build fully coalesced (binpass -> per-bucket LDS histogram -> scan ->
//    per-bucket LDS counting sort); bdst stored as ushort local ids.
//  * OVERLAP: one launch = GEMM(rel r) blocks + gather(rel r+1) blocks, no
//    inter-block deps (GEMM reads buf[r&1], gather writes buf[(r+1)&1]).
//    Hides 6 of 7 GEMMs per layer inside the gather launches.
//    [R6: gathers 48% HBM, GEMM ~30% -> sum < 6.3 TB/s ceiling]
//  * GEMM m97-style: global_load_lds w=16, unpadded 64B LDS rows, BK=64.
//  * Both accumulators bf16; classifier GEMM fused with ReLU+BN+Wc2 epilogue
//    (direct 100k x 2 output, no z1 roundtrip).
// Workspace ~256.8 MB.
// ---------------------------------------------------------------------------

#define NN 100000
#define NREL 7
#define NE 1600000
#define NB 128
#define BCAP 14336
#define BNODES 782

using uint = unsigned int;
using ushort_t = unsigned short;
using bf16x8 = __attribute__((ext_vector_type(8))) __bf16;
using f32x4 = __attribute__((ext_vector_type(4))) float;

__device__ __forceinline__ ushort_t f32_to_bf16(float f) {
    uint u = __float_as_uint(f);
    u += 0x7fffu + ((u >> 16) & 1u);
    return (ushort_t)(u >> 16);
}
__device__ __forceinline__ float bf16lo(uint u) { return __uint_as_float(u << 16); }
__device__ __forceinline__ float bf16hi(uint u) { return __uint_as_float(u & 0xffff0000u); }

__device__ __forceinline__ void gload16(const ushort_t* g, ushort_t* l) {
    __builtin_amdgcn_global_load_lds(
        (const __attribute__((address_space(1))) uint*)g,
        (__attribute__((address_space(3))) uint*)l, 16, 0, 0);
}

// ---------------- CSR build: pass 1 — LDS bucket binning -------------------
__global__ __launch_bounds__(256) void binpass_k(const int* __restrict__ edges,
                                                 int* __restrict__ bcnt,
                                                 int* __restrict__ bsrc,
                                                 ushort_t* __restrict__ bdst) {
    __shared__ int cnt[NB];
    __shared__ int lofs[NB];
    __shared__ int gbase[NB];
    __shared__ int wtot[2];
    __shared__ int stotal;
    __shared__ uint2 stage[4096];
    __shared__ unsigned char bb[4096];
    int r = blockIdx.y;
    int t = threadIdx.x;
    if (t < NB) cnt[t] = 0;
    __syncthreads();
    int e0 = blockIdx.x * 4096;
    uint2 mypair[16];
    int myrb[16];
#pragma unroll
    for (int i = 0; i < 16; ++i) {
        int e = e0 + i * 256 + t;
        if (e < NE) {
            int s = edges[(size_t)(2 * r) * NE + e];
            int d = edges[(size_t)(2 * r + 1) * NE + e];
            int b = d / BNODES;
            int rank = atomicAdd(&cnt[b], 1);
            myrb[i] = (rank << 7) | b;
            mypair[i] = make_uint2((uint)s, (uint)d);
        } else {
            myrb[i] = -1;
        }
    }
    __syncthreads();
    {
        int c = (t < NB) ? cnt[t] : 0;
        int lane = t & 63, wv = t >> 6;
        int x = c;
#pragma unroll
        for (int off = 1; off < 64; off <<= 1) {
            int y = __shfl_up(x, off);
            if (lane >= off) x += y;
        }
        if (t < NB && lane == 63) wtot[wv] = x;
        __syncthreads();
        if (t < NB) {
            int excl = x - c + (wv ? wtot[0] : 0);
            lofs[t] = excl;
            gbase[t] = atomicAdd(&bcnt[r * NB + t], c);
            if (t == NB - 1) stotal = excl + c;
        }
    }
    __syncthreads();
#pragma unroll
    for (int i = 0; i < 16; ++i) {
        if (myrb[i] >= 0) {
            int b = myrb[i] & 127;
            int p = lofs[b] + (myrb[i] >> 7);
            stage[p] = mypair[i];
            bb[p] = (unsigned char)b;
        }
    }
    __syncthreads();
    int total = stotal;
    for (int p = t; p < total; p += 256) {
        int b = bb[p];
        uint2 pr = stage[p];
        int gpos = gbase[b] + (p - lofs[b]);
        if (gpos < BCAP) {
            size_t o = ((size_t)r * NB + b) * BCAP + gpos;
            bsrc[o] = (int)pr.x;
            bdst[o] = (ushort_t)(pr.y - (uint)b * BNODES);
        }
    }
}

// ---------------- CSR build: per-bucket LDS degree histogram ---------------
__global__ __launch_bounds__(1024) void deg_bucket_k(const ushort_t* __restrict__ bdst,
                                                     const int* __restrict__ bcnt,
                                                     int* __restrict__ deg) {
    __shared__ int hist[BNODES];
    int rb = blockIdx.x;
    int r = rb >> 7, b = rb & 127;
    int node0 = b * BNODES;
    int nnodes = NN - node0 < BNODES ? NN - node0 : BNODES;
    int t = threadIdx.x;
    for (int i = t; i < nnodes; i += 1024) hist[i] = 0;
    __syncthreads();
    int cb = bcnt[rb];
    if (cb > BCAP) cb = BCAP;
    const ushort_t* src = bdst + (size_t)rb * BCAP;
    for (int i = t; i < cb; i += 1024) {
        atomicAdd(&hist[(int)src[i]], 1);
    }
    __syncthreads();
    for (int i = t; i < nnodes; i += 1024) deg[r * NN + node0 + i] = hist[i];
}

// ---------------- CSR build: scan (deg -> rowptr) ----------------
__global__ void scan1_k(const int* __restrict__ deg, int* __restrict__ rowptr,
                        int* __restrict__ blk, int total) {
    __shared__ int wsum[4];
    int t = threadIdx.x;
    int base = blockIdx.x * 4096 + t * 16;
    int vals[16];
    int s = 0;
#pragma unroll
    for (int i = 0; i < 16; ++i) {
        int g = base + i;
        int v = (g < total) ? deg[g] : 0;
        vals[i] = s;
        s += v;
    }
    int lane = t & 63, w = t >> 6;
    int x = s;
    for (int off = 1; off < 64; off <<= 1) {
        int y = __shfl_up(x, off);
        if (lane >= off) x += y;
    }
    if (lane == 63) wsum[w] = x;
    __syncthreads();
    if (t == 0) {
        int a = 0;
#pragma unroll
        for (int k = 0; k < 4; ++k) { int b = wsum[k]; wsum[k] = a; a += b; }
        blk[blockIdx.x] = a;
    }
    __syncthreads();
    int excl = x - s + wsum[w];
#pragma unroll
    for (int i = 0; i < 16; ++i) {
        int g = base + i;
        if (g < total) rowptr[g] = excl + vals[i];
    }
}

__global__ void scan2_k(int* blk, int nb) {
    if (threadIdx.x == 0 && blockIdx.x == 0) {
        int a = 0;
        for (int i = 0; i < nb; ++i) { int b = blk[i]; blk[i] = a; a += b; }
    }
}

__global__ void scan3_k(int* __restrict__ rowptr, const int* __restrict__ blk, int total) {
    int t = threadIdx.x;
    int add = blk[blockIdx.x];
    int base = blockIdx.x * 4096 + t * 16;
#pragma unroll
    for (int i = 0; i < 16; ++i) {
        int g = base + i;
        if (g < total) rowptr[g] += add;
    }
}

// ---------------- CSR build: per-bucket LDS counting sort ------------------
__global__ __launch_bounds__(1024) void bucket_sort_k(const int* __restrict__ bsrc,
                                                      const ushort_t* __restrict__ bdst,
                                                      const int* __restrict__ bcnt,
                                                      const int* __restrict__ rowptr,
                                                      int* __restrict__ csr) {
    __shared__ int stage[BCAP];
    __shared__ int lcur[BNODES];
    int rb = blockIdx.x;
    int r = rb >> 7, b = rb & 127;
    int node0 = b * BNODES;
    int nnodes = NN - node0 < BNODES ? NN - node0 : BNODES;
    int t = threadIdx.x;
    int rowbase = rowptr[r * NN + node0];
    int endIdx = r * NN + node0 + nnodes;
    int rowend = (endIdx < NREL * NN) ? rowptr[endIdx] : (NREL * NE);
    int truen = rowend - rowbase;
    int nent = truen < BCAP ? truen : BCAP;
    for (int i = t; i < nent; i += 1024) stage[i] = 0;
    for (int i = t; i < nnodes; i += 1024) lcur[i] = 0;
    __syncthreads();
    int cb = bcnt[rb];
    if (cb > BCAP) cb = BCAP;
    for (int i = t; i < cb; i += 1024) {
        int local = (int)bdst[(size_t)rb * BCAP + i];
        int sv = bsrc[(size_t)rb * BCAP + i];
        int pos = rowptr[r * NN + node0 + local] - rowbase + atomicAdd(&lcur[local], 1);
        if (pos < BCAP) stage[pos] = sv;
    }
    __syncthreads();
    for (int i = t; i < nent; i += 1024) csr[rowbase + i] = stage[i];
    for (int i = nent + t; i < truen; i += 1024) csr[rowbase + i] = 0;
}

// ---------------- conversions / weight prep ----------------
__global__ void convert_x_k(const float* __restrict__ x, ushort_t* __restrict__ xb) {
    int idx = blockIdx.x * 256 + threadIdx.x;
    int n = idx >> 5;
    int c = idx & 31;
    float4 v = *(const float4*)(x + (size_t)n * 128 + c * 4);
    ushort4 o;
    o.x = f32_to_bf16(v.x); o.y = f32_to_bf16(v.y);
    o.z = f32_to_bf16(v.z); o.w = f32_to_bf16(v.w);
    *(ushort4*)(xb + (size_t)n * 128 + c * 4) = o;
}

// B1cat: panel0 = [sum Wself1 | Wneigh1_0] (N=256 x K=256), then panels r=1..6
// of Wneigh1_r (N=256 x K=128) at elem offset 65536 + (r-1)*32768.
__global__ void prep_B1cat_k(const float* __restrict__ Wself, const float* __restrict__ Wneigh,
                             const float* __restrict__ b, ushort_t* __restrict__ Bcat,
                             float* __restrict__ bs) {
    int idx = blockIdx.x * 256 + threadIdx.x;  // 262144 + 256
    if (idx < 65536) {
        int n = idx >> 8, k = idx & 255;
        float v;
        if (k < 128) {
            v = 0.f;
#pragma unroll
            for (int r = 0; r < 7; ++r) v += Wself[((size_t)r * 128 + k) * 256 + n];
        } else {
            v = Wneigh[(size_t)(k - 128) * 256 + n];  // rel 0
        }
        Bcat[(size_t)n * 256 + k] = f32_to_bf16(v);
    } else if (idx < 262144) {
        int j = idx - 65536;
        int r = (j >> 15) + 1;          // rel 1..6
        int rem = j & 32767;
        int n = rem >> 7, k = rem & 127;
        Bcat[65536 + (size_t)(r - 1) * 32768 + n * 128 + k] =
            f32_to_bf16(Wneigh[((size_t)r * 128 + k) * 256 + n]);
    } else if (idx < 262400) {
        int i = idx - 262144;
        float s = 0.f;
#pragma unroll
        for (int r = 0; r < 7; ++r) s += b[r * 256 + i];
        bs[i] = s * (1.f / 7.f);
    }
}

// B2cat: panel0 = [sum Wself2 | Wneigh2_0] (N=256 x K=512), then panels r=1..6
// of Wneigh2_r (N=256 x K=256) at elem offset 131072 + (r-1)*65536.
__global__ void prep_B2cat_k(const float* __restrict__ Wself, const float* __restrict__ Wneigh,
                             const float* __restrict__ b, ushort_t* __restrict__ Bcat,
                             float* __restrict__ bs) {
    int idx = blockIdx.x * 256 + threadIdx.x;  // 524288 + 256
    if (idx < 131072) {
        int n = idx >> 9, k = idx & 511;
        float v;
        if (k < 256) {
            v = 0.f;
#pragma unroll
            for (int r = 0; r < 7; ++r) v += Wself[((size_t)r * 256 + k) * 256 + n];
        } else {
            v = Wneigh[(size_t)(k - 256) * 256 + n];  // rel 0
        }
        Bcat[(size_t)n * 512 + k] = f32_to_bf16(v);
    } else if (idx < 524288) {
        int j = idx - 131072;
        int r = (j >> 16) + 1;
        int rem = j & 65535;
        int n = rem >> 8, k = rem & 255;
        Bcat[131072 + (size_t)(r - 1) * 65536 + n * 256 + k] =
            f32_to_bf16(Wneigh[((size_t)r * 256 + k) * 256 + n]);
    } else if (idx < 524544) {
        int i = idx - 524288;
        float s = 0.f;
#pragma unroll
        for (int r = 0; r < 7; ++r) s += b[r * 256 + i];
        bs[i] = s * (1.f / 7.f);
    }
}

__global__ void prep_cls_k(const float* __restrict__ Wc1, const float* __restrict__ bn_g,
                           const float* __restrict__ bn_b, const float* __restrict__ Wc2,
                           const float* __restrict__ bc2, ushort_t* __restrict__ Wc1T,
                           float* __restrict__ W2p, float* __restrict__ cp) {
    int idx = blockIdx.x * 256 + threadIdx.x;
    if (idx < 128 * 256) {
        int n = idx >> 8;
        int k = idx & 255;
        Wc1T[(size_t)n * 256 + k] = f32_to_bf16(Wc1[(size_t)k * 128 + n]);
    } else if (idx < 128 * 256 + 256) {
        int e = idx - 128 * 256;
        int d = e >> 1, j = e & 1;
        W2p[e] = bn_g[d] * rsqrtf(1.f + 1e-5f) * Wc2[d * 2 + j];
    } else if (idx < 128 * 256 + 256 + 2) {
        int j = idx - (128 * 256 + 256);
        float s = bc2[j];
        for (int d = 0; d < 128; ++d) s += bn_b[d] * Wc2[d * 2 + j];
        cp[j] = s;
    }
}

// ---------------- gather body: neighbor mean via CSR, 8-wide unroll --------
template <int V>
__device__ __forceinline__ void gather_body(
    const ushort_t* __restrict__ T, const int* __restrict__ csr,
    const int* __restrict__ rowptr, const int* __restrict__ deg,
    ushort_t* __restrict__ Mout, int r, int bid, int t) {
    int n = bid * 4 + (t >> 6);
    if (n >= NN) return;
    int lane = t & 63;
    int pair = r * NN + n;
    int start = rowptr[pair];
    int cnt = deg[pair];
    float aLo[2][2] = {{0.f, 0.f}, {0.f, 0.f}};
    float aHi[2][2] = {{0.f, 0.f}, {0.f, 0.f}};
    int j = 0;
    if (V == 1) {
        const uint* Tu = (const uint*)T;
        for (; j + 8 <= cnt; j += 8) {
            int s[8];
#pragma unroll
            for (int q = 0; q < 8; ++q) s[q] = csr[start + j + q];
            uint u[8];
#pragma unroll
            for (int q = 0; q < 8; ++q) u[q] = Tu[(size_t)s[q] * 64 + lane];
#pragma unroll
            for (int q = 0; q < 8; ++q) {
                aLo[0][q & 1] += bf16lo(u[q]);
                aHi[0][q & 1] += bf16hi(u[q]);
            }
        }
        for (; j < cnt; ++j) {
            uint u = Tu[(size_t)csr[start + j] * 64 + lane];
            aLo[0][0] += bf16lo(u);
            aHi[0][0] += bf16hi(u);
        }
        float inv = 1.f / (float)(cnt > 1 ? cnt : 1);
        uint lo = f32_to_bf16((aLo[0][0] + aLo[0][1]) * inv);
        uint hi = f32_to_bf16((aHi[0][0] + aHi[0][1]) * inv);
        ((uint*)(Mout + (size_t)n * 128))[lane] = lo | (hi << 16);
    } else {
        const uint2* Tu = (const uint2*)T;
        for (; j + 8 <= cnt; j += 8) {
            int s[8];
#pragma unroll
            for (int q = 0; q < 8; ++q) s[q] = csr[start + j + q];
            uint2 u[8];
#pragma unroll
            for (int q = 0; q < 8; ++q) u[q] = Tu[(size_t)s[q] * 64 + lane];
#pragma unroll
            for (int q = 0; q < 8; ++q) {
                aLo[0][q & 1] += bf16lo(u[q].x);
                aHi[0][q & 1] += bf16hi(u[q].x);
                aLo[1][q & 1] += bf16lo(u[q].y);
                aHi[1][q & 1] += bf16hi(u[q].y);
            }
        }
        for (; j < cnt; ++j) {
            uint2 u = Tu[(size_t)csr[start + j] * 64 + lane];
            aLo[0][0] += bf16lo(u.x);
            aHi[0][0] += bf16hi(u.x);
            aLo[1][0] += bf16lo(u.y);
            aHi[1][0] += bf16hi(u.y);
        }
        float inv = 1.f / (float)(cnt > 1 ? cnt : 1);
        uint lox = f32_to_bf16((aLo[0][0] + aLo[0][1]) * inv);
        uint hix = f32_to_bf16((aHi[0][0] + aHi[0][1]) * inv);
        uint loy = f32_to_bf16((aLo[1][0] + aLo[1][1]) * inv);
        uint hiy = f32_to_bf16((aHi[1][0] + aHi[1][1]) * inv);
        ((uint2*)(Mout + (size_t)n * 256))[lane] =
            make_uint2(lox | (hix << 16), loy | (hiy << 16));
    }
}

// ---------------- GEMM body (m97-style staging) ----------------
// A = [A0 | A1] along K (split at Ksplit; Ksplit=0 -> single A1).
// mode 2: Cbf16 = a*acc+bias   3: Cbf16 += a*acc
__device__ __forceinline__ void gemm_body(
    ushort_t* lA, ushort_t* lB,
    const ushort_t* __restrict__ A0, const ushort_t* __restrict__ A1,
    int lda, int Ksplit, const ushort_t* __restrict__ BT, void* __restrict__ Cv,
    int M, int N, int K, float alpha, const float* __restrict__ bias, int mode,
    int bx, int by, int t) {
    int gr0 = bx * 128;
    int gc0 = by * 128;
    int w = t >> 6, lane = t & 63;
    int wr = w >> 1, wc = w & 1;
    int lm = lane & 15, quad = lane >> 4;
    int srow = lane >> 2;
    int schunk = (lane & 3) * 8;
    f32x4 acc[4][4];
#pragma unroll
    for (int i = 0; i < 4; ++i)
#pragma unroll
        for (int j = 0; j < 4; ++j) acc[i][j] = (f32x4){0.f, 0.f, 0.f, 0.f};

    for (int kk = 0; kk < K; kk += 64) {
        const ushort_t* Asrc = (kk < Ksplit) ? A0 : A1;
        int kloc = (kk < Ksplit) ? kk : (kk - Ksplit);
        __syncthreads();
#pragma unroll
        for (int s = 0; s < 2; ++s) {
#pragma unroll
            for (int j = 0; j < 2; ++j) {
                int rb = (j * 4 + w) * 16;
                int row = rb + srow;
                int gr = gr0 + row;
                if (gr < M)
                    gload16(Asrc + (size_t)gr * lda + kloc + s * 32 + schunk,
                            lA + s * 4096 + rb * 32);
                gload16(BT + (size_t)(gc0 + row) * K + kk + s * 32 + schunk,
                        lB + s * 4096 + rb * 32);
            }
        }
        __syncthreads();
#pragma unroll
        for (int s = 0; s < 2; ++s) {
            bf16x8 af[4], bfr[4];
#pragma unroll
            for (int f = 0; f < 4; ++f) {
                af[f] = *(const bf16x8*)(lA + s * 4096 + (wr * 64 + f * 16 + lm) * 32 + quad * 8);
                bfr[f] = *(const bf16x8*)(lB + s * 4096 + (wc * 64 + f * 16 + lm) * 32 + quad * 8);
            }
#pragma unroll
            for (int fr = 0; fr < 4; ++fr)
#pragma unroll
                for (int fc = 0; fc < 4; ++fc)
                    acc[fr][fc] = __builtin_amdgcn_mfma_f32_16x16x32_bf16(
                        af[fr], bfr[fc], acc[fr][fc], 0, 0, 0);
        }
    }
    ushort_t* Cb = (ushort_t*)Cv;
#pragma unroll
    for (int fr = 0; fr < 4; ++fr) {
#pragma unroll
        for (int fc = 0; fc < 4; ++fc) {
#pragma unroll
            for (int i = 0; i < 4; ++i) {
                int row = wr * 64 + fr * 16 + quad * 4 + i;
                int col = wc * 64 + fc * 16 + lm;
                int gr = gr0 + row;
                int gc = gc0 + col;
                if (gr < M) {
                    size_t o = (size_t)gr * N + gc;
                    float v = acc[fr][fc][i] * alpha;
                    if (mode == 2) v += bias ? bias[gc] : 0.f;
                    if (mode == 3) v += __uint_as_float((uint)Cb[o] << 16);
                    Cb[o] = f32_to_bf16(v);
                }
            }
        }
    }
}

// ---------------- mixed launch: GEMM blocks (first) + gather blocks --------
template <int V>
__global__ __launch_bounds__(256) void mixed_k(
    const ushort_t* A0, const ushort_t* A1, int lda, int Ksplit,
    const ushort_t* BT, void* Cv, int M, int N, int K, float alpha,
    const float* bias, int mode, int nGemmX, int nGemmY,
    const ushort_t* T, const int* csr, const int* rowptr, const int* deg,
    ushort_t* Mout, int r) {
    __shared__ __align__(16) ushort_t lA[2 * 4096];
    __shared__ __align__(16) ushort_t lB[2 * 4096];
    int bid = blockIdx.x;
    int ng = nGemmX * nGemmY;
    if (bid < ng) {
        gemm_body(lA, lB, A0, A1, lda, Ksplit, BT, Cv, M, N, K, alpha, bias, mode,
                  bid % nGemmX, bid / nGemmX, threadIdx.x);
    } else {
        gather_body<V>(T, csr, rowptr, deg, Mout, r, bid - ng, threadIdx.x);
    }
}

// ---------------- standalone gather / GEMM ----------------
template <int V>
__global__ __launch_bounds__(256) void gather_mean_k(
    const ushort_t* __restrict__ T, const int* __restrict__ csr,
    const int* __restrict__ rowptr, const int* __restrict__ deg,
    ushort_t* __restrict__ Mout, int r) {
    gather_body<V>(T, csr, rowptr, deg, Mout, r, blockIdx.x, threadIdx.x);
}

__global__ __launch_bounds__(256) void gemm_dual(
    const ushort_t* __restrict__ A0, const ushort_t* __restrict__ A1,
    int lda, int Ksplit, const ushort_t* __restrict__ BT, void* __restrict__ Cv,
    int M, int N, int K, float alpha, const float* __restrict__ bias, int mode) {
    __shared__ __align__(16) ushort_t lA[2 * 4096];
    __shared__ __align__(16) ushort_t lB[2 * 4096];
    gemm_body(lA, lB, A0, A1, lda, Ksplit, BT, Cv, M, N, K, alpha, bias, mode,
              blockIdx.x, blockIdx.y, threadIdx.x);
}

// ---------------- classifier GEMM fused: relu+BN+Wc2 epilogue -> out -------
// A: NN x 256 bf16. BT: 128 x 256 bf16 (Wc1T). out: NN x 2 f32.
__global__ __launch_bounds__(256) void gemm_cls_k(
    const ushort_t* __restrict__ A, const ushort_t* __restrict__ BT,
    const float* __restrict__ bc1, const float* __restrict__ W2p,
    const float* __restrict__ cp, float* __restrict__ out) {
    __shared__ __align__(16) ushort_t lA[2 * 4096];
    __shared__ __align__(16) ushort_t lB[2 * 4096];
    __shared__ float red[256];
    int t = threadIdx.x;
    int gr0 = blockIdx.x * 128;
    int w = t >> 6, lane = t & 63;
    int wr = w >> 1, wc = w & 1;
    int lm = lane & 15, quad = lane >> 4;
    int srow = lane >> 2;
    int schunk = (lane & 3) * 8;
    f32x4 acc[4][4];
#pragma unroll
    for (int i = 0; i < 4; ++i)
#pragma unroll
        for (int j = 0; j < 4; ++j) acc[i][j] = (f32x4){0.f, 0.f, 0.f, 0.f};
    for (int kk = 0; kk < 256; kk += 64) {
        __syncthreads();
#pragma unroll
        for (int s = 0; s < 2; ++s) {
#pragma unroll
            for (int j = 0; j < 2; ++j) {
                int rb = (j * 4 + w) * 16;
                int row = rb + srow;
                int gr = gr0 + row;
                if (gr < NN)
                    gload16(A + (size_t)gr * 256 + kk + s * 32 + schunk,
                            lA + s * 4096 + rb * 32);
                gload16(BT + (size_t)row * 256 + kk + s * 32 + schunk,
                        lB + s * 4096 + rb * 32);
            }
        }
        __syncthreads();
#pragma unroll
        for (int s = 0; s < 2; ++s) {
            bf16x8 af[4], bfr[4];
#pragma unroll
            for (int f = 0; f < 4; ++f) {
                af[f] = *(const bf16x8*)(lA + s * 4096 + (wr * 64 + f * 16 + lm) * 32 + quad * 8);
                bfr[f] = *(const bf16x8*)(lB + s * 4096 + (wc * 64 + f * 16 + lm) * 32 + quad * 8);
            }
#pragma unroll
            for (int fr = 0; fr < 4; ++fr)
#pragma unroll
                for (int fc = 0; fc < 4; ++fc)
                    acc[fr][fc] = __builtin_amdgcn_mfma_f32_16x16x32_bf16(
                        af[fr], bfr[fc], acc[fr][fc], 0, 0, 0);
        }
    }
    red[t] = 0.f;
    __syncthreads();
#pragma unroll
    for (int fr = 0; fr < 4; ++fr) {
#pragma unroll
        for (int i = 0; i < 4; ++i) {
            int row = wr * 64 + fr * 16 + quad * 4 + i;
            float p0 = 0.f, p1 = 0.f;
#pragma unroll
            for (int fc = 0; fc < 4; ++fc) {
                int col = wc * 64 + fc * 16 + lm;
                float z = fmaxf(acc[fr][fc][i] + bc1[col], 0.f);
                p0 += z * W2p[col * 2];
                p1 += z * W2p[col * 2 + 1];
            }
            atomicAdd(&red[row * 2], p0);
            atomicAdd(&red[row * 2 + 1], p1);
        }
    }
    __syncthreads();
    if (t < 128) {
        int gr = gr0 + t;
        if (gr < NN) {
            out[(size_t)gr * 2] = red[t * 2] + cp[0];
            out[(size_t)gr * 2 + 1] = red[t * 2 + 1] + cp[1];
        }
    }
}

// ---------------- LayerNorm + ReLU, bf16 in -> bf16 out ----------------
__global__ __launch_bounds__(256) void ln_relu_b_k(
    const ushort_t* __restrict__ h, const float* __restrict__ g,
    const float* __restrict__ b, ushort_t* __restrict__ out) {
    int n = blockIdx.x * 4 + (threadIdx.x >> 6);
    if (n >= NN) return;
    int lane = threadIdx.x & 63;
    uint2 u = ((const uint2*)(h + (size_t)n * 256))[lane];
    float v0 = bf16lo(u.x), v1 = bf16hi(u.x), v2 = bf16lo(u.y), v3 = bf16hi(u.y);
    float s = v0 + v1 + v2 + v3;
    float q = v0 * v0 + v1 * v1 + v2 * v2 + v3 * v3;
#pragma unroll
    for (int m = 1; m < 64; m <<= 1) {
        s += __shfl_xor(s, m);
        q += __shfl_xor(q, m);
    }
    float mean = s * (1.f / 256.f);
    float var = q * (1.f / 256.f) - mean * mean;
    float rs = rsqrtf(var + 1e-5f);
    float4 gv = *(const float4*)(g + lane * 4);
    float4 bv = *(const float4*)(b + lane * 4);
    float y0 = fmaxf((v0 - mean) * rs * gv.x + bv.x, 0.f);
    float y1 = fmaxf((v1 - mean) * rs * gv.y + bv.y, 0.f);
    float y2 = fmaxf((v2 - mean) * rs * gv.z + bv.z, 0.f);
    float y3 = fmaxf((v3 - mean) * rs * gv.w + bv.w, 0.f);
    uint2 o;
    o.x = (uint)f32_to_bf16(y0) | ((uint)f32_to_bf16(y1) << 16);
    o.y = (uint)f32_to_bf16(y2) | ((uint)f32_to_bf16(y3) << 16);
    *(uint2*)(out + (size_t)n * 256 + lane * 4) = o;
}

// ---------------- workspace layout (~256.8 MB) ------------------------------
constexpr size_t O_DEG   = 0;
constexpr size_t O_ROW   = 2800128;
constexpr size_t O_BLK   = 5600256;
constexpr size_t O_CSR   = 5601280;        // 44,800,000
constexpr size_t O_B1C   = 50401280;       // 524,288
constexpr size_t O_B2C   = 50925568;       // 1,048,576
constexpr size_t O_WC1T  = 51974144;       // 65,536
constexpr size_t O_W2P   = 52039680;
constexpr size_t O_CP    = 52040704;
constexpr size_t O_B1S   = 52040960;
constexpr size_t O_B2S   = 52041984;
constexpr size_t O_XB    = 52043008;       // xb bf16 25,600,000
constexpr size_t O_MA1   = 77643008;       // 25,600,000
constexpr size_t O_MB1   = 103243008;      // 25,600,000
constexpr size_t O_HACC1 = 128843008;      // bf16 51,200,000 -> 180,043,008
// CSR-build scratch (dead before convert_x):
constexpr size_t O_BCNT  = 52043008;       // pad 4096
constexpr size_t O_BSRC  = 52047104;       // int 51,380,224
constexpr size_t O_BDST  = 103427328;      // ushort 25,690,112
// L2 aliases:
constexpr size_t O_H1B   = O_XB;           // 51,200,000
constexpr size_t O_MA2   = 103243008;      // 51,200,000
constexpr size_t O_MB2   = 154443008;      // 51,200,000
constexpr size_t O_HACC2 = 205643008;      // bf16 51,200,000 -> 256,843,008
constexpr size_t O_H2B   = O_XB;           // (h1b dead after L2 gathers+GEMMs)
constexpr size_t WS_REQUIRED = 256843008;

extern "C" void kernel_launch(void* const* d_in, const int* in_sizes, int n_in,
                              void* d_out, int out_size, void* d_ws, size_t ws_size,
                              hipStream_t stream) {
    (void)in_sizes; (void)n_in;
    const float* features = (const float*)d_in[0];
    const int* edges = (const int*)d_in[1];
    const float* Wself1 = (const float*)d_in[2];
    const float* Wneigh1 = (const float*)d_in[3];
    const float* b1 = (const float*)d_in[4];
    const float* Wself2 = (const float*)d_in[5];
    const float* Wneigh2 = (const float*)d_in[6];
    const float* b2 = (const float*)d_in[7];
    const float* ln_g = (const float*)d_in[8];
    const float* ln_b = (const float*)d_in[9];
    const float* Wc1 = (const float*)d_in[10];
    const float* bc1 = (const float*)d_in[11];
    const float* bn_g = (const float*)d_in[12];
    const float* bn_b = (const float*)d_in[13];
    const float* Wc2 = (const float*)d_in[14];
    const float* bc2 = (const float*)d_in[15];
    float* out = (float*)d_out;
    char* ws = (char*)d_ws;

    if (ws_size < WS_REQUIRED) {
        hipMemsetAsync(d_out, 0, (size_t)out_size * 4, stream);
        return;
    }

    int* deg = (int*)(ws + O_DEG);
    int* rowptr = (int*)(ws + O_ROW);
    int* blk = (int*)(ws + O_BLK);
    int* csr = (int*)(ws + O_CSR);
    ushort_t* B1cat = (ushort_t*)(ws + O_B1C);
    ushort_t* B2cat = (ushort_t*)(ws + O_B2C);
    ushort_t* Wc1T = (ushort_t*)(ws + O_WC1T);
    float* W2p = (float*)(ws + O_W2P);
    float* cp = (float*)(ws + O_CP);
    float* b1s = (float*)(ws + O_B1S);
    float* b2s = (float*)(ws + O_B2S);
    ushort_t* xb = (ushort_t*)(ws + O_XB);
    ushort_t* hacc1 = (ushort_t*)(ws + O_HACC1);
    ushort_t* h1b = (ushort_t*)(ws + O_H1B);
    ushort_t* hacc2 = (ushort_t*)(ws + O_HACC2);
    ushort_t* h2b = (ushort_t*)(ws + O_H2B);
    int* bcnt = (int*)(ws + O_BCNT);
    int* bsrc = (int*)(ws + O_BSRC);
    ushort_t* bdst = (ushort_t*)(ws + O_BDST);
    ushort_t* m1[2] = {(ushort_t*)(ws + O_MA1), (ushort_t*)(ws + O_MB1)};
    ushort_t* m2[2] = {(ushort_t*)(ws + O_MA2), (ushort_t*)(ws + O_MB2)};

    hipMemsetAsync(ws + O_BCNT, 0, 4096, stream);

    // ---- CSR build ----
    binpass_k<<<dim3(391, 7, 1), 256, 0, stream>>>(edges, bcnt, bsrc, bdst);
    deg_bucket_k<<<896, 1024, 0, stream>>>(bdst, bcnt, deg);
    scan1_k<<<171, 256, 0, stream>>>(deg, rowptr, blk, NREL * NN);
    scan2_k<<<1, 64, 0, stream>>>(blk, 171);
    scan3_k<<<171, 256, 0, stream>>>(rowptr, blk, NREL * NN);
    bucket_sort_k<<<896, 1024, 0, stream>>>(bsrc, bdst, bcnt, rowptr, csr);

    // ---- weight prep + x -> bf16 ----
    convert_x_k<<<12500, 256, 0, stream>>>(features, xb);
    prep_B1cat_k<<<1025, 256, 0, stream>>>(Wself1, Wneigh1, b1, B1cat, b1s);
    prep_B2cat_k<<<2050, 256, 0, stream>>>(Wself2, Wneigh2, b2, B2cat, b2s);
    prep_cls_k<<<130, 256, 0, stream>>>(Wc1, bn_g, bn_b, Wc2, bc2, Wc1T, W2p, cp);

    const int NG = 782 * 2;  // GEMM blocks per mixed launch
    const float A7 = 1.f / 7.f;

    // ---- layer 1: overlap GEMM(r) with gather(r+1) ----
    gather_mean_k<1><<<25000, 256, 0, stream>>>(xb, csr, rowptr, deg, m1[0], 0);
    // launch: GEMM0 [xb|m0] K=256 + gather r1
    mixed_k<1><<<NG + 25000, 256, 0, stream>>>(
        xb, m1[0], 128, 128, B1cat, hacc1, NN, 256, 256, A7, b1s, 2, 782, 2,
        xb, csr, rowptr, deg, m1[1], 1);
    for (int r = 1; r <= 5; ++r) {
        mixed_k<1><<<NG + 25000, 256, 0, stream>>>(
            m1[r & 1], m1[r & 1], 128, 0, B1cat + 65536 + (size_t)(r - 1) * 32768,
            hacc1, NN, 256, 128, A7, nullptr, 3, 782, 2,
            xb, csr, rowptr, deg, m1[(r + 1) & 1], r + 1);
    }
    gemm_dual<<<dim3(782, 2, 1), 256, 0, stream>>>(
        m1[0], m1[0], 128, 0, B1cat + 65536 + 5 * 32768, hacc1,
        NN, 256, 128, A7, nullptr, 3);
    ln_relu_b_k<<<25000, 256, 0, stream>>>(hacc1, ln_g, ln_b, h1b);

    // ---- layer 2 ----
    gather_mean_k<2><<<25000, 256, 0, stream>>>(h1b, csr, rowptr, deg, m2[0], 0);
    mixed_k<2><<<NG + 25000, 256, 0, stream>>>(
        h1b, m2[0], 256, 256, B2cat, hacc2, NN, 256, 512, A7, b2s, 2, 782, 2,
        h1b, csr, rowptr, deg, m2[1], 1);
    for (int r = 1; r <= 5; ++r) {
        mixed_k<2><<<NG + 25000, 256, 0, stream>>>(
            m2[r & 1], m2[r & 1], 256, 0, B2cat + 131072 + (size_t)(r - 1) * 65536,
            hacc2, NN, 256, 256, A7, nullptr, 3, 782, 2,
            h1b, csr, rowptr, deg, m2[(r + 1) & 1], r + 1);
    }
    gemm_dual<<<dim3(782, 2, 1), 256, 0, stream>>>(
        m2[0], m2[0], 256, 0, B2cat + 131072 + 5 * 65536, hacc2,
        NN, 256, 256, A7, nullptr, 3);
    ln_relu_b_k<<<25000, 256, 0, stream>>>(hacc2, ln_g + 256, ln_b + 256, h2b);

    // ---- classifier (fused epilogue -> out) ----
    gemm_cls_k<<<782, 256, 0, stream>>>(h2b, Wc1T, bc1, W2p, cp, out);
}

// Round 8
// 2832.916 us; speedup vs baseline: 1.1776x; 1.1776x over previous
//
#include <hip/hip_runtime.h>
#include <hip/hip_bf16.h>
#include <cstdint>

// ---------------------------------------------------------------------------
// HeteroGNN: 2-layer hetero-SAGE (7 rel, 1.6M edges) + classifier, 100k nodes.
// Design C7 (= R6 skeleton + full-N GEMM + fused classifier + fewer launches):
//  * CSR build fully coalesced (binpass -> per-bucket LDS histogram -> scan ->
//    per-bucket LDS counting sort); bdst as ushort local ids. [R4/R7 verified]
//  * Pairwise-merged dual-A GEMMs per layer (4 GEMMs, K=2D). [R5/R6 verified]
//  * GEMM: 128x256 full-N tile (A read ONCE per block), m97-style
//    global_load_lds w=16, unpadded 64B LDS rows, BK=64. acc bf16.
//  * R7 LESSON: no gather+GEMM fusion — unified kernels impose GEMM's
//    32KB LDS/68 VGPR on gather blocks, collapsing occupancy 72%->29%.
//  * Gathers launch 2 relations per dispatch (gridDim.y=2).
//  * Classifier GEMM fused with ReLU+BN+Wc2 epilogue -> direct 100k x 2 out.
// Workspace ~256.8 MB (layout identical to R6/R7, known to fit).
// ---------------------------------------------------------------------------

#define NN 100000
#define NREL 7
#define NE 1600000
#define NB 128
#define BCAP 14336
#define BNODES 782

using uint = unsigned int;
using ushort_t = unsigned short;
using bf16x8 = __attribute__((ext_vector_type(8))) __bf16;
using f32x4 = __attribute__((ext_vector_type(4))) float;

__device__ __forceinline__ ushort_t f32_to_bf16(float f) {
    uint u = __float_as_uint(f);
    u += 0x7fffu + ((u >> 16) & 1u);
    return (ushort_t)(u >> 16);
}
__device__ __forceinline__ float bf16lo(uint u) { return __uint_as_float(u << 16); }
__device__ __forceinline__ float bf16hi(uint u) { return __uint_as_float(u & 0xffff0000u); }

__device__ __forceinline__ void gload16(const ushort_t* g, ushort_t* l) {
    __builtin_amdgcn_global_load_lds(
        (const __attribute__((address_space(1))) uint*)g,
        (__attribute__((address_space(3))) uint*)l, 16, 0, 0);
}

// ---------------- CSR build: pass 1 — LDS bucket binning -------------------
__global__ __launch_bounds__(256) void binpass_k(const int* __restrict__ edges,
                                                 int* __restrict__ bcnt,
                                                 int* __restrict__ bsrc,
                                                 ushort_t* __restrict__ bdst) {
    __shared__ int cnt[NB];
    __shared__ int lofs[NB];
    __shared__ int gbase[NB];
    __shared__ int wtot[2];
    __shared__ int stotal;
    __shared__ uint2 stage[4096];
    __shared__ unsigned char bb[4096];
    int r = blockIdx.y;
    int t = threadIdx.x;
    if (t < NB) cnt[t] = 0;
    __syncthreads();
    int e0 = blockIdx.x * 4096;
    uint2 mypair[16];
    int myrb[16];
#pragma unroll
    for (int i = 0; i < 16; ++i) {
        int e = e0 + i * 256 + t;
        if (e < NE) {
            int s = edges[(size_t)(2 * r) * NE + e];
            int d = edges[(size_t)(2 * r + 1) * NE + e];
            int b = d / BNODES;
            int rank = atomicAdd(&cnt[b], 1);
            myrb[i] = (rank << 7) | b;
            mypair[i] = make_uint2((uint)s, (uint)d);
        } else {
            myrb[i] = -1;
        }
    }
    __syncthreads();
    {
        int c = (t < NB) ? cnt[t] : 0;
        int lane = t & 63, wv = t >> 6;
        int x = c;
#pragma unroll
        for (int off = 1; off < 64; off <<= 1) {
            int y = __shfl_up(x, off);
            if (lane >= off) x += y;
        }
        if (t < NB && lane == 63) wtot[wv] = x;
        __syncthreads();
        if (t < NB) {
            int excl = x - c + (wv ? wtot[0] : 0);
            lofs[t] = excl;
            gbase[t] = atomicAdd(&bcnt[r * NB + t], c);
            if (t == NB - 1) stotal = excl + c;
        }
    }
    __syncthreads();
#pragma unroll
    for (int i = 0; i < 16; ++i) {
        if (myrb[i] >= 0) {
            int b = myrb[i] & 127;
            int p = lofs[b] + (myrb[i] >> 7);
            stage[p] = mypair[i];
            bb[p] = (unsigned char)b;
        }
    }
    __syncthreads();
    int total = stotal;
    for (int p = t; p < total; p += 256) {
        int b = bb[p];
        uint2 pr = stage[p];
        int gpos = gbase[b] + (p - lofs[b]);
        if (gpos < BCAP) {
            size_t o = ((size_t)r * NB + b) * BCAP + gpos;
            bsrc[o] = (int)pr.x;
            bdst[o] = (ushort_t)(pr.y - (uint)b * BNODES);
        }
    }
}

// ---------------- CSR build: per-bucket LDS degree histogram ---------------
__global__ __launch_bounds__(1024) void deg_bucket_k(const ushort_t* __restrict__ bdst,
                                                     const int* __restrict__ bcnt,
                                                     int* __restrict__ deg) {
    __shared__ int hist[BNODES];
    int rb = blockIdx.x;
    int r = rb >> 7, b = rb & 127;
    int node0 = b * BNODES;
    int nnodes = NN - node0 < BNODES ? NN - node0 : BNODES;
    int t = threadIdx.x;
    for (int i = t; i < nnodes; i += 1024) hist[i] = 0;
    __syncthreads();
    int cb = bcnt[rb];
    if (cb > BCAP) cb = BCAP;
    const ushort_t* src = bdst + (size_t)rb * BCAP;
    for (int i = t; i < cb; i += 1024) {
        atomicAdd(&hist[(int)src[i]], 1);
    }
    __syncthreads();
    for (int i = t; i < nnodes; i += 1024) deg[r * NN + node0 + i] = hist[i];
}

// ---------------- CSR build: scan (deg -> rowptr) ----------------
__global__ void scan1_k(const int* __restrict__ deg, int* __restrict__ rowptr,
                        int* __restrict__ blk, int total) {
    __shared__ int wsum[4];
    int t = threadIdx.x;
    int base = blockIdx.x * 4096 + t * 16;
    int vals[16];
    int s = 0;
#pragma unroll
    for (int i = 0; i < 16; ++i) {
        int g = base + i;
        int v = (g < total) ? deg[g] : 0;
        vals[i] = s;
        s += v;
    }
    int lane = t & 63, w = t >> 6;
    int x = s;
    for (int off = 1; off < 64; off <<= 1) {
        int y = __shfl_up(x, off);
        if (lane >= off) x += y;
    }
    if (lane == 63) wsum[w] = x;
    __syncthreads();
    if (t == 0) {
        int a = 0;
#pragma unroll
        for (int k = 0; k < 4; ++k) { int b = wsum[k]; wsum[k] = a; a += b; }
        blk[blockIdx.x] = a;
    }
    __syncthreads();
    int excl = x - s + wsum[w];
#pragma unroll
    for (int i = 0; i < 16; ++i) {
        int g = base + i;
        if (g < total) rowptr[g] = excl + vals[i];
    }
}

__global__ void scan2_k(int* blk, int nb) {
    if (threadIdx.x == 0 && blockIdx.x == 0) {
        int a = 0;
        for (int i = 0; i < nb; ++i) { int b = blk[i]; blk[i] = a; a += b; }
    }
}

__global__ void scan3_k(int* __restrict__ rowptr, const int* __restrict__ blk, int total) {
    int t = threadIdx.x;
    int add = blk[blockIdx.x];
    int base = blockIdx.x * 4096 + t * 16;
#pragma unroll
    for (int i = 0; i < 16; ++i) {
        int g = base + i;
        if (g < total) rowptr[g] += add;
    }
}

// ---------------- CSR build: per-bucket LDS counting sort ------------------
__global__ __launch_bounds__(1024) void bucket_sort_k(const int* __restrict__ bsrc,
                                                      const ushort_t* __restrict__ bdst,
                                                      const int* __restrict__ bcnt,
                                                      const int* __restrict__ rowptr,
                                                      int* __restrict__ csr) {
    __shared__ int stage[BCAP];
    __shared__ int lcur[BNODES];
    int rb = blockIdx.x;
    int r = rb >> 7, b = rb & 127;
    int node0 = b * BNODES;
    int nnodes = NN - node0 < BNODES ? NN - node0 : BNODES;
    int t = threadIdx.x;
    int rowbase = rowptr[r * NN + node0];
    int endIdx = r * NN + node0 + nnodes;
    int rowend = (endIdx < NREL * NN) ? rowptr[endIdx] : (NREL * NE);
    int truen = rowend - rowbase;
    int nent = truen < BCAP ? truen : BCAP;
    for (int i = t; i < nent; i += 1024) stage[i] = 0;
    for (int i = t; i < nnodes; i += 1024) lcur[i] = 0;
    __syncthreads();
    int cb = bcnt[rb];
    if (cb > BCAP) cb = BCAP;
    for (int i = t; i < cb; i += 1024) {
        int local = (int)bdst[(size_t)rb * BCAP + i];
        int sv = bsrc[(size_t)rb * BCAP + i];
        int pos = rowptr[r * NN + node0 + local] - rowbase + atomicAdd(&lcur[local], 1);
        if (pos < BCAP) stage[pos] = sv;
    }
    __syncthreads();
    for (int i = t; i < nent; i += 1024) csr[rowbase + i] = stage[i];
    for (int i = nent + t; i < truen; i += 1024) csr[rowbase + i] = 0;
}

// ---------------- merged weight prep + x->bf16 (block-partitioned) ---------
// blocks [0,12500): convert_x; [12500,13525): B1cat; [13525,15575): B2cat;
// [15575,15705): classifier prep.
__global__ void prep_all_k(const float* __restrict__ x, ushort_t* __restrict__ xb,
                           const float* __restrict__ Ws1, const float* __restrict__ Wn1,
                           const float* __restrict__ b1, ushort_t* __restrict__ B1cat,
                           float* __restrict__ b1s,
                           const float* __restrict__ Ws2, const float* __restrict__ Wn2,
                           const float* __restrict__ b2, ushort_t* __restrict__ B2cat,
                           float* __restrict__ b2s,
                           const float* __restrict__ Wc1, const float* __restrict__ bn_g,
                           const float* __restrict__ bn_b, const float* __restrict__ Wc2,
                           const float* __restrict__ bc2, ushort_t* __restrict__ Wc1T,
                           float* __restrict__ W2p, float* __restrict__ cp) {
    int blk = blockIdx.x;
    int t = threadIdx.x;
    if (blk < 12500) {
        int idx = blk * 256 + t;
        int n = idx >> 5;
        int c = idx & 31;
        float4 v = *(const float4*)(x + (size_t)n * 128 + c * 4);
        ushort4 o;
        o.x = f32_to_bf16(v.x); o.y = f32_to_bf16(v.y);
        o.z = f32_to_bf16(v.z); o.w = f32_to_bf16(v.w);
        *(ushort4*)(xb + (size_t)n * 128 + c * 4) = o;
    } else if (blk < 13525) {
        // B1cat: 4 panels N=256 x K=256: g0=[sumWself1|Wn0], g=[Wn(2g-1)|Wn(2g)]
        int idx = (blk - 12500) * 256 + t;
        if (idx < 262144) {
            int g = idx >> 16;
            int rem = idx & 65535;
            int n = rem >> 8, k = rem & 255;
            float v;
            if (g == 0 && k < 128) {
                v = 0.f;
#pragma unroll
                for (int r = 0; r < 7; ++r) v += Ws1[((size_t)r * 128 + k) * 256 + n];
            } else {
                int k2 = k & 127;
                int rel = (g == 0) ? 0 : (2 * g - 1 + (k >> 7));
                v = Wn1[((size_t)rel * 128 + k2) * 256 + n];
            }
            B1cat[(size_t)g * 65536 + n * 256 + k] = f32_to_bf16(v);
        } else if (idx < 262400) {
            int i = idx - 262144;
            float s = 0.f;
#pragma unroll
            for (int r = 0; r < 7; ++r) s += b1[r * 256 + i];
            b1s[i] = s * (1.f / 7.f);
        }
    } else if (blk < 15575) {
        // B2cat: 4 panels N=256 x K=512
        int idx = (blk - 13525) * 256 + t;
        if (idx < 524288) {
            int g = idx >> 17;
            int rem = idx & 131071;
            int n = rem >> 9, k = rem & 511;
            float v;
            if (g == 0 && k < 256) {
                v = 0.f;
#pragma unroll
                for (int r = 0; r < 7; ++r) v += Ws2[((size_t)r * 256 + k) * 256 + n];
            } else {
                int k2 = k & 255;
                int rel = (g == 0) ? 0 : (2 * g - 1 + (k >> 8));
                v = Wn2[((size_t)rel * 256 + k2) * 256 + n];
            }
            B2cat[(size_t)g * 131072 + n * 512 + k] = f32_to_bf16(v);
        } else if (idx < 524544) {
            int i = idx - 524288;
            float s = 0.f;
#pragma unroll
            for (int r = 0; r < 7; ++r) s += b2[r * 256 + i];
            b2s[i] = s * (1.f / 7.f);
        }
    } else {
        int idx = (blk - 15575) * 256 + t;
        if (idx < 128 * 256) {
            int n = idx >> 8;
            int k = idx & 255;
            Wc1T[(size_t)n * 256 + k] = f32_to_bf16(Wc1[(size_t)k * 128 + n]);
        } else if (idx < 128 * 256 + 256) {
            int e = idx - 128 * 256;
            int d = e >> 1, j = e & 1;
            W2p[e] = bn_g[d] * rsqrtf(1.f + 1e-5f) * Wc2[d * 2 + j];
        } else if (idx < 128 * 256 + 256 + 2) {
            int j = idx - (128 * 256 + 256);
            float s = bc2[j];
            for (int d = 0; d < 128; ++d) s += bn_b[d] * Wc2[d * 2 + j];
            cp[j] = s;
        }
    }
}

// ---------------- gather body: neighbor mean via CSR, 8-wide unroll --------
template <int V>
__device__ __forceinline__ void gather_body(
    const ushort_t* __restrict__ T, const int* __restrict__ csr,
    const int* __restrict__ rowptr, const int* __restrict__ deg,
    ushort_t* __restrict__ Mout, int r, int bid, int t) {
    int n = bid * 4 + (t >> 6);
    if (n >= NN) return;
    int lane = t & 63;
    int pair = r * NN + n;
    int start = rowptr[pair];
    int cnt = deg[pair];
    float aLo[2][2] = {{0.f, 0.f}, {0.f, 0.f}};
    float aHi[2][2] = {{0.f, 0.f}, {0.f, 0.f}};
    int j = 0;
    if (V == 1) {
        const uint* Tu = (const uint*)T;
        for (; j + 8 <= cnt; j += 8) {
            int s[8];
#pragma unroll
            for (int q = 0; q < 8; ++q) s[q] = csr[start + j + q];
            uint u[8];
#pragma unroll
            for (int q = 0; q < 8; ++q) u[q] = Tu[(size_t)s[q] * 64 + lane];
#pragma unroll
            for (int q = 0; q < 8; ++q) {
                aLo[0][q & 1] += bf16lo(u[q]);
                aHi[0][q & 1] += bf16hi(u[q]);
            }
        }
        for (; j < cnt; ++j) {
            uint u = Tu[(size_t)csr[start + j] * 64 + lane];
            aLo[0][0] += bf16lo(u);
            aHi[0][0] += bf16hi(u);
        }
        float inv = 1.f / (float)(cnt > 1 ? cnt : 1);
        uint lo = f32_to_bf16((aLo[0][0] + aLo[0][1]) * inv);
        uint hi = f32_to_bf16((aHi[0][0] + aHi[0][1]) * inv);
        ((uint*)(Mout + (size_t)n * 128))[lane] = lo | (hi << 16);
    } else {
        const uint2* Tu = (const uint2*)T;
        for (; j + 8 <= cnt; j += 8) {
            int s[8];
#pragma unroll
            for (int q = 0; q < 8; ++q) s[q] = csr[start + j + q];
            uint2 u[8];
#pragma unroll
            for (int q = 0; q < 8; ++q) u[q] = Tu[(size_t)s[q] * 64 + lane];
#pragma unroll
            for (int q = 0; q < 8; ++q) {
                aLo[0][q & 1] += bf16lo(u[q].x);
                aHi[0][q & 1] += bf16hi(u[q].x);
                aLo[1][q & 1] += bf16lo(u[q].y);
                aHi[1][q & 1] += bf16hi(u[q].y);
            }
        }
        for (; j < cnt; ++j) {
            uint2 u = Tu[(size_t)csr[start + j] * 64 + lane];
            aLo[0][0] += bf16lo(u.x);
            aHi[0][0] += bf16hi(u.x);
            aLo[1][0] += bf16lo(u.y);
            aHi[1][0] += bf16hi(u.y);
        }
        float inv = 1.f / (float)(cnt > 1 ? cnt : 1);
        uint lox = f32_to_bf16((aLo[0][0] + aLo[0][1]) * inv);
        uint hix = f32_to_bf16((aHi[0][0] + aHi[0][1]) * inv);
        uint loy = f32_to_bf16((aLo[1][0] + aLo[1][1]) * inv);
        uint hiy = f32_to_bf16((aHi[1][0] + aHi[1][1]) * inv);
        ((uint2*)(Mout + (size_t)n * 256))[lane] =
            make_uint2(lox | (hix << 16), loy | (hiy << 16));
    }
}

template <int V>
__global__ __launch_bounds__(256) void gather_mean_k(
    const ushort_t* __restrict__ T, const int* __restrict__ csr,
    const int* __restrict__ rowptr, const int* __restrict__ deg,
    ushort_t* __restrict__ Mout, int r) {
    gather_body<V>(T, csr, rowptr, deg, Mout, r, blockIdx.x, threadIdx.x);
}

// two relations per dispatch: y=0 -> rel rA -> MoutA; y=1 -> rel rA+1 -> MoutB
template <int V>
__global__ __launch_bounds__(256) void gather_pair_k(
    const ushort_t* __restrict__ T, const int* __restrict__ csr,
    const int* __restrict__ rowptr, const int* __restrict__ deg,
    ushort_t* __restrict__ MoutA, ushort_t* __restrict__ MoutB, int rA) {
    int y = blockIdx.y;
    gather_body<V>(T, csr, rowptr, deg, y ? MoutB : MoutA, rA + y,
                   blockIdx.x, threadIdx.x);
}

// ---------------- full-N dual-A bf16 MFMA GEMM: tile 128(M) x 256(N) -------
// A = [A0 | A1] along K (split at Ksplit), both M x Ksplit row-major (lda).
// BT: 256 x K row-major bf16. C: M x 256 bf16.
// mode 2: C = a*acc+bias   3: C += a*acc
// A is read ONCE per block (vs twice with 128x128 tiles).
__global__ __launch_bounds__(256) void gemm_wide(
    const ushort_t* __restrict__ A0, const ushort_t* __restrict__ A1,
    int lda, int Ksplit, const ushort_t* __restrict__ BT,
    ushort_t* __restrict__ Cb, int M, int K, float alpha,
    const float* __restrict__ bias, int mode) {
    __shared__ __align__(16) ushort_t lA[2 * 4096];  // 128 rows x 32, 2 subpanels
    __shared__ __align__(16) ushort_t lB[2 * 8192];  // 256 rows x 32, 2 subpanels
    int t = threadIdx.x;
    int gr0 = blockIdx.x * 128;
    int w = t >> 6, lane = t & 63;
    int wrr = w >> 1, wcc = w & 1;   // wave: M-half (64), N-half (128)
    int lm = lane & 15, quad = lane >> 4;
    int srow = lane >> 2;
    int schunk = (lane & 3) * 8;
    f32x4 acc[4][8];
#pragma unroll
    for (int i = 0; i < 4; ++i)
#pragma unroll
        for (int j = 0; j < 8; ++j) acc[i][j] = (f32x4){0.f, 0.f, 0.f, 0.f};

    for (int kk = 0; kk < K; kk += 64) {
        const ushort_t* Asrc = (kk < Ksplit) ? A0 : A1;
        int kloc = (kk < Ksplit) ? kk : (kk - Ksplit);
        __syncthreads();
#pragma unroll
        for (int s = 0; s < 2; ++s) {
#pragma unroll
            for (int j = 0; j < 2; ++j) {         // A: 128 rows
                int rb = (j * 4 + w) * 16;
                int gr = gr0 + rb + srow;
                if (gr < M)
                    gload16(Asrc + (size_t)gr * lda + kloc + s * 32 + schunk,
                            lA + s * 4096 + rb * 32);
            }
#pragma unroll
            for (int j = 0; j < 4; ++j) {         // B: 256 rows
                int rb = (j * 4 + w) * 16;
                gload16(BT + (size_t)(rb + srow) * K + kk + s * 32 + schunk,
                        lB + s * 8192 + rb * 32);
            }
        }
        __syncthreads();
#pragma unroll
        for (int s = 0; s < 2; ++s) {
            bf16x8 af[4], bfr[8];
#pragma unroll
            for (int f = 0; f < 4; ++f)
                af[f] = *(const bf16x8*)(lA + s * 4096 + (wrr * 64 + f * 16 + lm) * 32 + quad * 8);
#pragma unroll
            for (int f = 0; f < 8; ++f)
                bfr[f] = *(const bf16x8*)(lB + s * 8192 + (wcc * 128 + f * 16 + lm) * 32 + quad * 8);
#pragma unroll
            for (int fr = 0; fr < 4; ++fr)
#pragma unroll
                for (int fc = 0; fc < 8; ++fc)
                    acc[fr][fc] = __builtin_amdgcn_mfma_f32_16x16x32_bf16(
                        af[fr], bfr[fc], acc[fr][fc], 0, 0, 0);
        }
    }
#pragma unroll
    for (int fr = 0; fr < 4; ++fr) {
#pragma unroll
        for (int fc = 0; fc < 8; ++fc) {
#pragma unroll
            for (int i = 0; i < 4; ++i) {
                int row = wrr * 64 + fr * 16 + quad * 4 + i;
                int col = wcc * 128 + fc * 16 + lm;
                int gr = gr0 + row;
                if (gr < M) {
                    size_t o = (size_t)gr * 256 + col;
                    float v = acc[fr][fc][i] * alpha;
                    if (mode == 2) v += bias ? bias[col] : 0.f;
                    if (mode == 3) v += __uint_as_float((uint)Cb[o] << 16);
                    Cb[o] = f32_to_bf16(v);
                }
            }
        }
    }
}

// ---------------- classifier GEMM fused: relu+BN+Wc2 epilogue -> out -------
__global__ __launch_bounds__(256) void gemm_cls_k(
    const ushort_t* __restrict__ A, const ushort_t* __restrict__ BT,
    const float* __restrict__ bc1, const float* __restrict__ W2p,
    const float* __restrict__ cp, float* __restrict__ out) {
    __shared__ __align__(16) ushort_t lA[2 * 4096];
    __shared__ __align__(16) ushort_t lB[2 * 4096];
    __shared__ float red[256];
    int t = threadIdx.x;
    int gr0 = blockIdx.x * 128;
    int w = t >> 6, lane = t & 63;
    int wr = w >> 1, wc = w & 1;
    int lm = lane & 15, quad = lane >> 4;
    int srow = lane >> 2;
    int schunk = (lane & 3) * 8;
    f32x4 acc[4][4];
#pragma unroll
    for (int i = 0; i < 4; ++i)
#pragma unroll
        for (int j = 0; j < 4; ++j) acc[i][j] = (f32x4){0.f, 0.f, 0.f, 0.f};
    for (int kk = 0; kk < 256; kk += 64) {
        __syncthreads();
#pragma unroll
        for (int s = 0; s < 2; ++s) {
#pragma unroll
            for (int j = 0; j < 2; ++j) {
                int rb = (j * 4 + w) * 16;
                int row = rb + srow;
                int gr = gr0 + row;
                if (gr < NN)
                    gload16(A + (size_t)gr * 256 + kk + s * 32 + schunk,
                            lA + s * 4096 + rb * 32);
                gload16(BT + (size_t)row * 256 + kk + s * 32 + schunk,
                        lB + s * 4096 + rb * 32);
            }
        }
        __syncthreads();
#pragma unroll
        for (int s = 0; s < 2; ++s) {
            bf16x8 af[4], bfr[4];
#pragma unroll
            for (int f = 0; f < 4; ++f) {
                af[f] = *(const bf16x8*)(lA + s * 4096 + (wr * 64 + f * 16 + lm) * 32 + quad * 8);
                bfr[f] = *(const bf16x8*)(lB + s * 4096 + (wc * 64 + f * 16 + lm) * 32 + quad * 8);
            }
#pragma unroll
            for (int fr = 0; fr < 4; ++fr)
#pragma unroll
                for (int fc = 0; fc < 4; ++fc)
                    acc[fr][fc] = __builtin_amdgcn_mfma_f32_16x16x32_bf16(
                        af[fr], bfr[fc], acc[fr][fc], 0, 0, 0);
        }
    }
    red[t] = 0.f;
    __syncthreads();
#pragma unroll
    for (int fr = 0; fr < 4; ++fr) {
#pragma unroll
        for (int i = 0; i < 4; ++i) {
            int row = wr * 64 + fr * 16 + quad * 4 + i;
            float p0 = 0.f, p1 = 0.f;
#pragma unroll
            for (int fc = 0; fc < 4; ++fc) {
                int col = wc * 64 + fc * 16 + lm;
                float z = fmaxf(acc[fr][fc][i] + bc1[col], 0.f);
                p0 += z * W2p[col * 2];
                p1 += z * W2p[col * 2 + 1];
            }
            atomicAdd(&red[row * 2], p0);
            atomicAdd(&red[row * 2 + 1], p1);
        }
    }
    __syncthreads();
    if (t < 128) {
        int gr = gr0 + t;
        if (gr < NN) {
            out[(size_t)gr * 2] = red[t * 2] + cp[0];
            out[(size_t)gr * 2 + 1] = red[t * 2 + 1] + cp[1];
        }
    }
}

// ---------------- LayerNorm + ReLU, bf16 in -> bf16 out ----------------
__global__ __launch_bounds__(256) void ln_relu_b_k(
    const ushort_t* __restrict__ h, const float* __restrict__ g,
    const float* __restrict__ b, ushort_t* __restrict__ out) {
    int n = blockIdx.x * 4 + (threadIdx.x >> 6);
    if (n >= NN) return;
    int lane = threadIdx.x & 63;
    uint2 u = ((const uint2*)(h + (size_t)n * 256))[lane];
    float v0 = bf16lo(u.x), v1 = bf16hi(u.x), v2 = bf16lo(u.y), v3 = bf16hi(u.y);
    float s = v0 + v1 + v2 + v3;
    float q = v0 * v0 + v1 * v1 + v2 * v2 + v3 * v3;
#pragma unroll
    for (int m = 1; m < 64; m <<= 1) {
        s += __shfl_xor(s, m);
        q += __shfl_xor(q, m);
    }
    float mean = s * (1.f / 256.f);
    float var = q * (1.f / 256.f) - mean * mean;
    float rs = rsqrtf(var + 1e-5f);
    float4 gv = *(const float4*)(g + lane * 4);
    float4 bv = *(const float4*)(b + lane * 4);
    float y0 = fmaxf((v0 - mean) * rs * gv.x + bv.x, 0.f);
    float y1 = fmaxf((v1 - mean) * rs * gv.y + bv.y, 0.f);
    float y2 = fmaxf((v2 - mean) * rs * gv.z + bv.z, 0.f);
    float y3 = fmaxf((v3 - mean) * rs * gv.w + bv.w, 0.f);
    uint2 o;
    o.x = (uint)f32_to_bf16(y0) | ((uint)f32_to_bf16(y1) << 16);
    o.y = (uint)f32_to_bf16(y2) | ((uint)f32_to_bf16(y3) << 16);
    *(uint2*)(out + (size_t)n * 256 + lane * 4) = o;
}

// ---------------- workspace layout (~256.8 MB, same as R6/R7) ---------------
constexpr size_t O_DEG   = 0;
constexpr size_t O_ROW   = 2800128;
constexpr size_t O_BLK   = 5600256;
constexpr size_t O_CSR   = 5601280;        // 44,800,000
constexpr size_t O_B1C   = 50401280;       // 524,288
constexpr size_t O_B2C   = 50925568;       // 1,048,576
constexpr size_t O_WC1T  = 51974144;       // 65,536
constexpr size_t O_W2P   = 52039680;
constexpr size_t O_CP    = 52040704;
constexpr size_t O_B1S   = 52040960;
constexpr size_t O_B2S   = 52041984;
constexpr size_t O_XB    = 52043008;       // xb bf16 25,600,000
constexpr size_t O_MA1   = 77643008;       // 25,600,000
constexpr size_t O_MB1   = 103243008;      // 25,600,000
constexpr size_t O_HACC1 = 128843008;      // bf16 51,200,000 -> 180,043,008
constexpr size_t O_BCNT  = 52043008;       // CSR scratch (dead before prep)
constexpr size_t O_BSRC  = 52047104;       // int 51,380,224
constexpr size_t O_BDST  = 103427328;      // ushort 25,690,112
constexpr size_t O_H1B   = O_XB;           // 51,200,000
constexpr size_t O_MA2   = 103243008;      // 51,200,000
constexpr size_t O_MB2   = 154443008;      // 51,200,000
constexpr size_t O_HACC2 = 205643008;      // bf16 51,200,000 -> 256,843,008
constexpr size_t O_H2B   = O_XB;
constexpr size_t WS_REQUIRED = 256843008;

extern "C" void kernel_launch(void* const* d_in, const int* in_sizes, int n_in,
                              void* d_out, int out_size, void* d_ws, size_t ws_size,
                              hipStream_t stream) {
    (void)in_sizes; (void)n_in;
    const float* features = (const float*)d_in[0];
    const int* edges = (const int*)d_in[1];
    const float* Wself1 = (const float*)d_in[2];
    const float* Wneigh1 = (const float*)d_in[3];
    const float* b1 = (const float*)d_in[4];
    const float* Wself2 = (const float*)d_in[5];
    const float* Wneigh2 = (const float*)d_in[6];
    const float* b2 = (const float*)d_in[7];
    const float* ln_g = (const float*)d_in[8];
    const float* ln_b = (const float*)d_in[9];
    const float* Wc1 = (const float*)d_in[10];
    const float* bc1 = (const float*)d_in[11];
    const float* bn_g = (const float*)d_in[12];
    const float* bn_b = (const float*)d_in[13];
    const float* Wc2 = (const float*)d_in[14];
    const float* bc2 = (const float*)d_in[15];
    float* out = (float*)d_out;
    char* ws = (char*)d_ws;

    if (ws_size < WS_REQUIRED) {
        hipMemsetAsync(d_out, 0, (size_t)out_size * 4, stream);
        return;
    }

    int* deg = (int*)(ws + O_DEG);
    int* rowptr = (int*)(ws + O_ROW);
    int* blk = (int*)(ws + O_BLK);
    int* csr = (int*)(ws + O_CSR);
    ushort_t* B1cat = (ushort_t*)(ws + O_B1C);
    ushort_t* B2cat = (ushort_t*)(ws + O_B2C);
    ushort_t* Wc1T = (ushort_t*)(ws + O_WC1T);
    float* W2p = (float*)(ws + O_W2P);
    float* cp = (float*)(ws + O_CP);
    float* b1s = (float*)(ws + O_B1S);
    float* b2s = (float*)(ws + O_B2S);
    ushort_t* xb = (ushort_t*)(ws + O_XB);
    ushort_t* hacc1 = (ushort_t*)(ws + O_HACC1);
    ushort_t* h1b = (ushort_t*)(ws + O_H1B);
    ushort_t* hacc2 = (ushort_t*)(ws + O_HACC2);
    ushort_t* h2b = (ushort_t*)(ws + O_H2B);
    int* bcnt = (int*)(ws + O_BCNT);
    int* bsrc = (int*)(ws + O_BSRC);
    ushort_t* bdst = (ushort_t*)(ws + O_BDST);
    ushort_t* mA1 = (ushort_t*)(ws + O_MA1);
    ushort_t* mB1 = (ushort_t*)(ws + O_MB1);
    ushort_t* mA2 = (ushort_t*)(ws + O_MA2);
    ushort_t* mB2 = (ushort_t*)(ws + O_MB2);

    hipMemsetAsync(ws + O_BCNT, 0, 4096, stream);

    // ---- CSR build ----
    binpass_k<<<dim3(391, 7, 1), 256, 0, stream>>>(edges, bcnt, bsrc, bdst);
    deg_bucket_k<<<896, 1024, 0, stream>>>(bdst, bcnt, deg);
    scan1_k<<<171, 256, 0, stream>>>(deg, rowptr, blk, NREL * NN);
    scan2_k<<<1, 64, 0, stream>>>(blk, 171);
    scan3_k<<<171, 256, 0, stream>>>(rowptr, blk, NREL * NN);
    bucket_sort_k<<<896, 1024, 0, stream>>>(bsrc, bdst, bcnt, rowptr, csr);

    // ---- merged prep (x->bf16 + all weight panels) ----
    prep_all_k<<<15705, 256, 0, stream>>>(features, xb,
                                          Wself1, Wneigh1, b1, B1cat, b1s,
                                          Wself2, Wneigh2, b2, B2cat, b2s,
                                          Wc1, bn_g, bn_b, Wc2, bc2, Wc1T, W2p, cp);

    const float A7 = 1.f / 7.f;

    // ---- layer 1: 4 paired full-N GEMMs, acc bf16 ----
    gather_mean_k<1><<<25000, 256, 0, stream>>>(xb, csr, rowptr, deg, mA1, 0);
    gemm_wide<<<782, 256, 0, stream>>>(xb, mA1, 128, 128, B1cat, hacc1,
                                       NN, 256, A7, b1s, 2);
    for (int g = 1; g < 4; ++g) {
        gather_pair_k<1><<<dim3(25000, 2, 1), 256, 0, stream>>>(
            xb, csr, rowptr, deg, mA1, mB1, 2 * g - 1);
        gemm_wide<<<782, 256, 0, stream>>>(mA1, mB1, 128, 128,
                                           B1cat + (size_t)g * 65536, hacc1,
                                           NN, 256, A7, nullptr, 3);
    }
    ln_relu_b_k<<<25000, 256, 0, stream>>>(hacc1, ln_g, ln_b, h1b);

    // ---- layer 2 ----
    gather_mean_k<2><<<25000, 256, 0, stream>>>(h1b, csr, rowptr, deg, mA2, 0);
    gemm_wide<<<782, 256, 0, stream>>>(h1b, mA2, 256, 256, B2cat, hacc2,
                                       NN, 512, A7, b2s, 2);
    for (int g = 1; g < 4; ++g) {
        gather_pair_k<2><<<dim3(25000, 2, 1), 256, 0, stream>>>(
            h1b, csr, rowptr, deg, mA2, mB2, 2 * g - 1);
        gemm_wide<<<782, 256, 0, stream>>>(mA2, mB2, 256, 256,
                                           B2cat + (size_t)g * 131072, hacc2,
                                           NN, 512, A7, nullptr, 3);
    }
    ln_relu_b_k<<<25000, 256, 0, stream>>>(hacc2, ln_g + 256, ln_b + 256, h2b);

    // ---- classifier (fused epilogue -> out) ----
    gemm_cls_k<<<782, 256, 0, stream>>>(h2b, Wc1T, bc1, W2p, cp, out);
}